// Round 21
// baseline (49.452 us; speedup 1.0000x reference)
//
#include <hip/hip_runtime.h>
#include <hip/hip_bf16.h>

#define TLEN 65536
#define NSEQ 32
#define MAXD 10000
#define SEGS 1024
#define SEGL (TLEN / SEGS)   // 64 steps per segment
#define BURN 32              // warm-up steps (validated R17-R20)

typedef float v2f __attribute__((ext_vector_type(2)));

__device__ __forceinline__ float rcp_(float x) { return __builtin_amdgcn_rcpf(x); }
__device__ __forceinline__ float ex2_(float x) { return __builtin_amdgcn_exp2f(x); }
__device__ __forceinline__ v2f mk2(float a, float b) { v2f r; r.x = a; r.y = b; return r; }
__device__ __forceinline__ v2f pfma(v2f a, v2f b, v2f c) {
    return __builtin_elementwise_fma(a, b, c);   // v_pk_fma_f32 (full rate)
}

template <int CTRL>
__device__ __forceinline__ float dpp_(float v) {
    return __uint_as_float(__builtin_amdgcn_mov_dpp(
        (int)__float_as_uint(v), CTRL, 0xF, 0xF, true));
}
template <int CTRL>
__device__ __forceinline__ v2f dpp2_(v2f v) {
    v2f r; r.x = dpp_<CTRL>(v.x); r.y = dpp_<CTRL>(v.y); return r;
}
#define QX1 0xB1   // quad_perm [1,0,3,2] -> lane^1 (pair exchange)

// ---------------------------------------------------------------------------
// GRU, segmented-parallel, THIRTY-TWO chains/wave (2-lane groups, packed
// f32). Chain = aligned lane pair; lane p = lane&1 owns hidden units
// {p, p+2, p+4, p+6} as hA=(h_p,h_{p+2}), hB=(h_{p+4},h_{p+6}); one
// quad_perm xor-1 exchange (dpp2 x2) yields the neighbor's four -> all 8 h
// per lane as 4 v2f. Each lane computes its 12 gate-rows (4 units x 3
// gates) as 4-deep pk_fma chains with xor-matched packed weights; 5 trans
// per unit (3 ex2 + 2 rcp, shared-rcp tail); packed update
// h' = [En*(Ez+h)+(h-Ez)]*rcp((1+Ez)(1+En)).
// SEGS=1024 -> 1024 waves = 1/SIMD, 96 steps/wave (64 live + 32 burn):
// steps/SIMD drop 160 (R19) -> 96 at ~1.6x issue/step -> net win in the
// stall-dominated regime (R20 showed TLP cannot help this body).
// pre_d: full 8-dot via own-partial + xor1-partial; staged in a float4
// (lane p owns slots 4p..4p+3), one float4 store per chunk per lane.
// Segments [seg*SEGL-burn, ...) from h=0; seg 0 exact; each pre_d element
// stored by exactly one lane -> deterministic.
// ---------------------------------------------------------------------------
__global__ __launch_bounds__(64, 1) void gru_kernel(
    const float* __restrict__ x,      // (NSEQ, TLEN)
    const float* __restrict__ w_ih,   // (24, 1)
    const float* __restrict__ w_hh,   // (24, 8) row-major
    const float* __restrict__ b_ih,   // (24,)
    const float* __restrict__ b_hh,   // (24,)
    const float* __restrict__ w_out,  // (1, 8)
    float* __restrict__ pre_d)        // (NSEQ, TLEN)
{
    const int lane = threadIdx.x & 63;
    const int q    = lane >> 1;              // 0..31: chain within the wave
    const int p    = lane & 1;               // half: units {p,p+2,p+4,p+6}
    const int seq  = blockIdx.y * 32 + q;
    const int seg  = blockIdx.x;

    const int burn    = (seg == 0) ? 0 : BURN;
    const int tstart  = seg * SEGL - burn;   // multiple of 8
    const int nch     = (burn + SEGL) / 8;   // total chunks of 8 steps
    const int wchunks = burn / 8;            // first live chunk index

    const float L2E = 1.44269504088896f;
    const float NEG = -L2E, POS2 = 2.0f * L2E;
    const int p1 = p ^ 1;

    // packed weights: row of unit u=p+2i, parts pair with {hA,hB,nA,nB}
    v2f wR[4][4], wZ[4][4], wN[4][4];
#pragma unroll
    for (int i = 0; i < 4; ++i) {
        const int u = p + 2 * i;
        const float* rowR = w_hh + (0  + u) * 8;
        const float* rowZ = w_hh + (8  + u) * 8;
        const float* rowN = w_hh + (16 + u) * 8;
        wR[i][0] = mk2(NEG * rowR[p],      NEG * rowR[p + 2]);
        wR[i][1] = mk2(NEG * rowR[p + 4],  NEG * rowR[p + 6]);
        wR[i][2] = mk2(NEG * rowR[p1],     NEG * rowR[p1 + 2]);
        wR[i][3] = mk2(NEG * rowR[p1 + 4], NEG * rowR[p1 + 6]);
        wZ[i][0] = mk2(NEG * rowZ[p],      NEG * rowZ[p + 2]);
        wZ[i][1] = mk2(NEG * rowZ[p + 4],  NEG * rowZ[p + 6]);
        wZ[i][2] = mk2(NEG * rowZ[p1],     NEG * rowZ[p1 + 2]);
        wZ[i][3] = mk2(NEG * rowZ[p1 + 4], NEG * rowZ[p1 + 6]);
        wN[i][0] = mk2(POS2 * rowN[p],      POS2 * rowN[p + 2]);
        wN[i][1] = mk2(POS2 * rowN[p + 4],  POS2 * rowN[p + 6]);
        wN[i][2] = mk2(POS2 * rowN[p1],     POS2 * rowN[p1 + 2]);
        wN[i][3] = mk2(POS2 * rowN[p1 + 4], POS2 * rowN[p1 + 6]);
    }
    float wirv[4], wizv[4], winv[4], brv[4], bzv[4], bniv[4], bnhv[4];
#pragma unroll
    for (int i = 0; i < 4; ++i) {
        const int u = p + 2 * i;
        wirv[i] = NEG  * w_ih[u];
        wizv[i] = NEG  * w_ih[8 + u];
        winv[i] = POS2 * w_ih[16 + u];
        brv[i]  = NEG  * (b_ih[u] + b_hh[u]);
        bzv[i]  = NEG  * (b_ih[8 + u] + b_hh[8 + u]);
        bniv[i] = POS2 * b_ih[16 + u];
        bnhv[i] = POS2 * b_hh[16 + u];
    }
    const v2f wovA = mk2(w_out[p],     w_out[p + 2]);
    const v2f wovB = mk2(w_out[p + 4], w_out[p + 6]);

    const float4* xs4 = (const float4*)(x + (size_t)seq * TLEN + tstart);
    float*        pd  = pre_d + (size_t)seq * TLEN + tstart;

    v2f hA = mk2(0.f, 0.f), hB = mk2(0.f, 0.f);
    float4 vst = make_float4(0.f, 0.f, 0.f, 0.f);  // slots 4p..4p+3

    float4 a0 = xs4[0], a1 = xs4[1];

#define GRU_STEP_CORE(XT)                                                     \
    {                                                                         \
    const v2f nA = dpp2_<QX1>(hA);                                            \
    const v2f nB = dpp2_<QX1>(hB);                                            \
    float ar[4], az[4], an[4], gn[4];                                         \
    _Pragma("unroll")                                                         \
    for (int i = 0; i < 4; ++i) {                                             \
        v2f tR = pfma(nB, wR[i][3], mk2(fmaf(XT, wirv[i], brv[i]), 0.f));     \
        tR = pfma(nA, wR[i][2], tR);                                          \
        tR = pfma(hB, wR[i][1], tR);                                          \
        tR = pfma(hA, wR[i][0], tR);                                          \
        ar[i] = tR.x + tR.y;                                                  \
        v2f tZ = pfma(nB, wZ[i][3], mk2(fmaf(XT, wizv[i], bzv[i]), 0.f));     \
        tZ = pfma(nA, wZ[i][2], tZ);                                          \
        tZ = pfma(hB, wZ[i][1], tZ);                                          \
        tZ = pfma(hA, wZ[i][0], tZ);                                          \
        az[i] = tZ.x + tZ.y;                                                  \
        v2f tN = pfma(nB, wN[i][3], mk2(bnhv[i], 0.f));                       \
        tN = pfma(nA, wN[i][2], tN);                                          \
        tN = pfma(hB, wN[i][1], tN);                                          \
        tN = pfma(hA, wN[i][0], tN);                                          \
        an[i] = tN.x + tN.y;                                                  \
        gn[i] = fmaf(XT, winv[i], bniv[i]);                                   \
    }                                                                         \
    float Ez[4], En[4];                                                       \
    _Pragma("unroll")                                                         \
    for (int i = 0; i < 4; ++i) {                                             \
        const float Er = ex2_(ar[i]);                                         \
        Ez[i] = ex2_(az[i]);                                                  \
        const float rr = rcp_(1.f + Er);                                      \
        const float nv = fmaf(rr, an[i], gn[i]);                              \
        En[i] = ex2_(nv);                                                     \
    }                                                                         \
    const v2f one = mk2(1.f, 1.f);                                            \
    const v2f EzA = mk2(Ez[0], Ez[1]), EzB = mk2(Ez[2], Ez[3]);               \
    const v2f EnA = mk2(En[0], En[1]), EnB = mk2(En[2], En[3]);               \
    const v2f PA = (one + EzA) * (one + EnA);                                 \
    const v2f PB = (one + EzB) * (one + EnB);                                 \
    const v2f QA = pfma(EnA, EzA + hA, hA - EzA);                             \
    const v2f QB = pfma(EnB, EzB + hB, hB - EzB);                             \
    hA = QA * mk2(rcp_(PA.x), rcp_(PA.y));                                    \
    hB = QB * mk2(rcp_(PB.x), rcp_(PB.y));                                    \
    }

    // ---------------- burn loop: no pre_d staging ----------------
    for (int c = 0; c < wchunks; ++c) {
        const int cn = c + 1;                // < nch always
        float4 n0 = xs4[cn * 2], n1 = xs4[cn * 2 + 1];

        float cx[8];
        cx[0]=a0.x; cx[1]=a0.y; cx[2]=a0.z; cx[3]=a0.w;
        cx[4]=a1.x; cx[5]=a1.y; cx[6]=a1.z; cx[7]=a1.w;

#pragma unroll
        for (int u = 0; u < 8; ++u) {
            GRU_STEP_CORE(cx[u])
        }
        a0 = n0; a1 = n1;
    }

    // ---------------- live loop: staging + stores ----------------
    for (int c = wchunks; c < nch; ++c) {
        const int cn = (c + 1 < nch) ? (c + 1) : c;
        float4 n0 = xs4[cn * 2], n1 = xs4[cn * 2 + 1];

        float cx[8];
        cx[0]=a0.x; cx[1]=a0.y; cx[2]=a0.z; cx[3]=a0.w;
        cx[4]=a1.x; cx[5]=a1.y; cx[6]=a1.z; cx[7]=a1.w;

#pragma unroll
        for (int u = 0; u < 8; ++u) {
            const int slot = (u - 1) & 7;    // compile-time per unroll iter

            // pre_d[t-1] = h_{t-1}.w_out: own 4-partial + xor1 partial
            float partial = fmaf(hA.y, wovA.y, hA.x * wovA.x);
            partial = fmaf(hB.x, wovB.x, partial);
            partial = fmaf(hB.y, wovB.y, partial);
            const float sd = partial + dpp_<QX1>(partial);
            const bool own = (p == (slot >> 2));
            if ((slot & 3) == 0)      vst.x = own ? sd : vst.x;
            else if ((slot & 3) == 1) vst.y = own ? sd : vst.y;
            else if ((slot & 3) == 2) vst.z = own ? sd : vst.z;
            else                      vst.w = own ? sd : vst.w;

            GRU_STEP_CORE(cx[u])

            // after u==0's select, chunk c-1 fully staged: float4/lane
            if (u == 0 && c > wchunks) {
                *(float4*)(pd + (c - 1) * 8 + 4 * p) = vst;
            }
        }
        a0 = n0; a1 = n1;
    }

    // tail: slot 7 = sd(last step); store final chunk
    {
        float partial = fmaf(hA.y, wovA.y, hA.x * wovA.x);
        partial = fmaf(hB.x, wovB.x, partial);
        partial = fmaf(hB.y, wovB.y, partial);
        const float sd = partial + dpp_<QX1>(partial);
        vst.w = (p == 1) ? sd : vst.w;
        *(float4*)(pd + (nch - 1) * 8 + 4 * p) = vst;
    }
#undef GRU_STEP_CORE
}

// ---------------------------------------------------------------------------
// Kernel 2 (R18, proven): fractional delay with LDS-staged tap window.
// ---------------------------------------------------------------------------
#define TBLK 4096
#define WIN  (TBLK + MAXD)   // 14096 floats, 56384 B

__global__ __launch_bounds__(1024, 1) void delay_kernel(
    const float* __restrict__ pre_d,  // (NSEQ, TLEN)
    const float* __restrict__ dt,     // (NSEQ, TLEN)
    float* __restrict__ y)            // (NSEQ, TLEN)
{
    __shared__ float w[WIN];
    const int tid = threadIdx.x;
    const int n   = blockIdx.y;
    const int t0  = blockIdx.x * TBLK;

    const float* pdn = pre_d + (size_t)n * TLEN;
    const int wbase  = t0 - MAXD;            // global t of w[0]; mult of 4

    for (int i = tid; i < WIN / 4; i += 1024) {
        const int gt = wbase + i * 4;        // whole quad same sign
        float4 v = make_float4(0.f, 0.f, 0.f, 0.f);
        if (gt >= 0) v = *(const float4*)(pdn + gt);
        *(float4*)(&w[i * 4]) = v;
    }
    __syncthreads();

    const int t = t0 + tid * 4;
    const float4 d4 = *(const float4*)(dt + (size_t)n * TLEN + t);
    float dv[4] = {d4.x, d4.y, d4.z, d4.w};
    float out[4];
#pragma unroll
    for (int e = 0; e < 4; ++e) {
        const float pq = (float)MAXD - dv[e];
        const float k0 = floorf(pq);
        const float fr = pq - k0;
        const int k0i  = (int)k0;
        const int k1i  = min(k0i + 1, MAXD);
        const int li0  = tid * 4 + e + k0i;
        const int li1  = tid * 4 + e + k1i;
        out[e] = fmaf(1.0f - fr, w[li0], fr * w[li1]);
    }
    float4 o = make_float4(out[0], out[1], out[2], out[3]);
    *(float4*)(y + (size_t)n * TLEN + t) = o;
}

extern "C" void kernel_launch(void* const* d_in, const int* in_sizes, int n_in,
                              void* d_out, int out_size, void* d_ws, size_t ws_size,
                              hipStream_t stream) {
    const float* x      = (const float*)d_in[0];
    const float* dtraj  = (const float*)d_in[1];
    const float* w_ih   = (const float*)d_in[3];
    const float* w_hh   = (const float*)d_in[4];
    const float* b_ih   = (const float*)d_in[5];
    const float* b_hh   = (const float*)d_in[6];
    const float* w_out  = (const float*)d_in[7];

    float* y     = (float*)d_out;                       // output 0: (32,1,65536)
    float* pre_d = (float*)d_out + (size_t)NSEQ * TLEN; // output 1

    // GRU: 32 chains/wave; 1024 waves -> 1 wave/SIMD
    gru_kernel<<<dim3(SEGS, NSEQ / 32), dim3(64), 0, stream>>>(
        x, w_ih, w_hh, b_ih, b_hh, w_out, pre_d);

    // Delay: LDS-staged window, 512 blocks x 1024 threads
    delay_kernel<<<dim3(TLEN / TBLK, NSEQ), dim3(1024), 0, stream>>>(
        pre_d, dtraj, y);
}

// Round 22
// 44.066 us; speedup vs baseline: 1.1222x; 1.1222x over previous
//
#include <hip/hip_runtime.h>
#include <hip/hip_bf16.h>

#define TLEN 65536
#define NSEQ 32
#define MAXD 10000
#define SEGS 512
#define SEGL (TLEN / SEGS)   // 128 steps per segment
#define BURN 32              // warm-up steps (validated R17-R21)

typedef float v2f __attribute__((ext_vector_type(2)));

__device__ __forceinline__ float rcp_(float x) { return __builtin_amdgcn_rcpf(x); }
__device__ __forceinline__ float ex2_(float x) { return __builtin_amdgcn_exp2f(x); }
__device__ __forceinline__ v2f mk2(float a, float b) { v2f r; r.x = a; r.y = b; return r; }
__device__ __forceinline__ v2f pfma(v2f a, v2f b, v2f c) {
    return __builtin_elementwise_fma(a, b, c);   // v_pk_fma_f32 (full rate)
}

template <int CTRL>
__device__ __forceinline__ float dpp_(float v) {
    return __uint_as_float(__builtin_amdgcn_mov_dpp(
        (int)__float_as_uint(v), CTRL, 0xF, 0xF, true));
}
template <int CTRL>
__device__ __forceinline__ v2f dpp2_(v2f v) {
    v2f r; r.x = dpp_<CTRL>(v.x); r.y = dpp_<CTRL>(v.y); return r;
}
// quad_perm controls: xor-1/2/3 within each 4-lane quad (quad-local).
#define QX1 0xB1   // quad_perm [1,0,3,2]
#define QX2 0x4E   // quad_perm [2,3,0,1]
#define QX3 0x1B   // quad_perm [3,2,1,0]

// ---------------------------------------------------------------------------
// GRU, segmented-parallel, 16 chains/wave (packed-f32) -- the measured
// optimum of the full knob space (R7..R21): chains/wave {1..32}->16,
// waves/SIMD {1,2,4}->1, SEGS {64..1024}->512, BURN {256..32}->32.
// Chain = 4-lane quad; lane p=lane&3 holds v2f h = (h_p, h_{p+4}).
// Butterfly: 3 packed quad_perms give all 8 h per lane. Row-j dot =
// 4 pk_fma + horiz add; weights pre-scaled by -log2e (r,z) / 2log2e (n);
// shared-rcp packed tail h' = [En*(Ez+h)+(h-Ez)]*rcp((1+Ez)(1+En)).
// Segments [seg*SEGL-burn, ...) from h=0; seg 0 exact; each pre_d element
// stored by exactly one wave -> deterministic.
// ---------------------------------------------------------------------------
__global__ __launch_bounds__(64, 1) void gru_kernel(
    const float* __restrict__ x,      // (NSEQ, TLEN)
    const float* __restrict__ w_ih,   // (24, 1)
    const float* __restrict__ w_hh,   // (24, 8) row-major
    const float* __restrict__ b_ih,   // (24,)
    const float* __restrict__ b_hh,   // (24,)
    const float* __restrict__ w_out,  // (1, 8)
    float* __restrict__ pre_d)        // (NSEQ, TLEN)
{
    const int lane = threadIdx.x & 63;
    const int q    = lane >> 2;              // 0..15: chain within the wave
    const int p    = lane & 3;               // owns hidden units p and p+4
    const int seq  = blockIdx.y * 16 + q;
    const int seg  = blockIdx.x;

    const int burn    = (seg == 0) ? 0 : BURN;
    const int tstart  = seg * SEGL - burn;   // multiple of 8
    const int nch     = (burn + SEGL) / 8;   // total chunks of 8 steps
    const int wchunks = burn / 8;            // first live chunk index

    const float L2E = 1.44269504088896f;
    const float NEG = -L2E, POS2 = 2.0f * L2E;

    // packed weights: index m pairs with hp[m] = (h_{p^m}, h_{(p^m)+4})
    v2f wrA[4], wrB[4], wzA[4], wzB[4], wnA[4], wnB[4];
#pragma unroll
    for (int m = 0; m < 4; ++m) {
        const int k = p ^ m;
        wrA[m] = mk2(NEG  * w_hh[(0  + p) * 8 + k], NEG  * w_hh[(0  + p) * 8 + k + 4]);
        wrB[m] = mk2(NEG  * w_hh[(4  + p) * 8 + k], NEG  * w_hh[(4  + p) * 8 + k + 4]);
        wzA[m] = mk2(NEG  * w_hh[(8  + p) * 8 + k], NEG  * w_hh[(8  + p) * 8 + k + 4]);
        wzB[m] = mk2(NEG  * w_hh[(12 + p) * 8 + k], NEG  * w_hh[(12 + p) * 8 + k + 4]);
        wnA[m] = mk2(POS2 * w_hh[(16 + p) * 8 + k], POS2 * w_hh[(16 + p) * 8 + k + 4]);
        wnB[m] = mk2(POS2 * w_hh[(20 + p) * 8 + k], POS2 * w_hh[(20 + p) * 8 + k + 4]);
    }
    const v2f wov = mk2(w_out[p], w_out[p + 4]);

    const float wir_p = NEG  * w_ih[p],      wir_q = NEG  * w_ih[4 + p];
    const float wiz_p = NEG  * w_ih[8 + p],  wiz_q = NEG  * w_ih[12 + p];
    const float win_p = POS2 * w_ih[16 + p], win_q = POS2 * w_ih[20 + p];
    const float br_p = NEG * (b_ih[p] + b_hh[p]);
    const float br_q = NEG * (b_ih[4 + p] + b_hh[4 + p]);
    const float bz_p = NEG * (b_ih[8 + p] + b_hh[8 + p]);
    const float bz_q = NEG * (b_ih[12 + p] + b_hh[12 + p]);
    const float bni_p = POS2 * b_ih[16 + p], bni_q = POS2 * b_ih[20 + p];
    const float bnh_p = POS2 * b_hh[16 + p], bnh_q = POS2 * b_hh[20 + p];

    const float4* xs4 = (const float4*)(x + (size_t)seq * TLEN + tstart);
    float*        pd  = pre_d + (size_t)seq * TLEN + tstart;

    v2f h   = mk2(0.f, 0.f);          // (h_p, h_{p+4}) of this quad's chain
    v2f vst = mk2(0.f, 0.f);          // staging: .x slots 0-3, .y slots 4-7

    float4 a0 = xs4[0], a1 = xs4[1];

#define GRU_STEP_CORE(XT)                                                     \
    v2f hp0 = h;                                                              \
    v2f hp1 = dpp2_<QX1>(h);                                                  \
    v2f hp2 = dpp2_<QX2>(h);                                                  \
    v2f hp3 = dpp2_<QX3>(h);                                                  \
    v2f aR = mk2(fmaf(XT, wir_p, br_p), 0.f);                                 \
    v2f bR = mk2(fmaf(XT, wir_q, br_q), 0.f);                                 \
    v2f aZ = mk2(fmaf(XT, wiz_p, bz_p), 0.f);                                 \
    v2f bZ = mk2(fmaf(XT, wiz_q, bz_q), 0.f);                                 \
    v2f aN = mk2(bnh_p, 0.f);                                                 \
    v2f bN = mk2(bnh_q, 0.f);                                                 \
    const float gn_p = fmaf(XT, win_p, bni_p);                                \
    const float gn_q = fmaf(XT, win_q, bni_q);                                \
    aR = pfma(hp0, wrA[0], aR); aR = pfma(hp1, wrA[1], aR);                   \
    aR = pfma(hp2, wrA[2], aR); aR = pfma(hp3, wrA[3], aR);                   \
    bR = pfma(hp0, wrB[0], bR); bR = pfma(hp1, wrB[1], bR);                   \
    bR = pfma(hp2, wrB[2], bR); bR = pfma(hp3, wrB[3], bR);                   \
    aZ = pfma(hp0, wzA[0], aZ); aZ = pfma(hp1, wzA[1], aZ);                   \
    aZ = pfma(hp2, wzA[2], aZ); aZ = pfma(hp3, wzA[3], aZ);                   \
    bZ = pfma(hp0, wzB[0], bZ); bZ = pfma(hp1, wzB[1], bZ);                   \
    bZ = pfma(hp2, wzB[2], bZ); bZ = pfma(hp3, wzB[3], bZ);                   \
    aN = pfma(hp0, wnA[0], aN); aN = pfma(hp1, wnA[1], aN);                   \
    aN = pfma(hp2, wnA[2], aN); aN = pfma(hp3, wnA[3], aN);                   \
    bN = pfma(hp0, wnB[0], bN); bN = pfma(hp1, wnB[1], bN);                   \
    bN = pfma(hp2, wnB[2], bN); bN = pfma(hp3, wnB[3], bN);                   \
    const float ar_p = aR.x + aR.y, ar_q = bR.x + bR.y;                       \
    const float az_p = aZ.x + aZ.y, az_q = bZ.x + bZ.y;                       \
    const float an_p = aN.x + aN.y, an_q = bN.x + bN.y;                       \
    const float Er_p = ex2_(ar_p), Er_q = ex2_(ar_q);                         \
    const float Ez_p = ex2_(az_p), Ez_q = ex2_(az_q);                         \
    const float r_p = rcp_(1.f + Er_p), r_q = rcp_(1.f + Er_q);               \
    const float nv_p = fmaf(r_p, an_p, gn_p);                                 \
    const float nv_q = fmaf(r_q, an_q, gn_q);                                 \
    const float En_p = ex2_(nv_p), En_q = ex2_(nv_q);                         \
    const v2f Ez = mk2(Ez_p, Ez_q);                                           \
    const v2f En = mk2(En_p, En_q);                                           \
    const v2f one = mk2(1.f, 1.f);                                            \
    const v2f P = (one + Ez) * (one + En);                                    \
    const v2f Q = pfma(En, Ez + h, h - Ez);                                   \
    const v2f rp = mk2(rcp_(P.x), rcp_(P.y));                                 \
    h = Q * rp;

    // ---------------- burn loop: no pre_d staging ----------------
    for (int c = 0; c < wchunks; ++c) {
        const int cn = c + 1;                // < nch always
        float4 n0 = xs4[cn * 2], n1 = xs4[cn * 2 + 1];

        float cx[8];
        cx[0]=a0.x; cx[1]=a0.y; cx[2]=a0.z; cx[3]=a0.w;
        cx[4]=a1.x; cx[5]=a1.y; cx[6]=a1.z; cx[7]=a1.w;

#pragma unroll
        for (int u = 0; u < 8; ++u) {
            GRU_STEP_CORE(cx[u])
        }
        a0 = n0; a1 = n1;
    }

    // ---------------- live loop: staging + stores ----------------
    for (int c = wchunks; c < nch; ++c) {
        const int cn = (c + 1 < nch) ? (c + 1) : c;
        float4 n0 = xs4[cn * 2], n1 = xs4[cn * 2 + 1];

        float cx[8];
        cx[0]=a0.x; cx[1]=a0.y; cx[2]=a0.z; cx[3]=a0.w;
        cx[4]=a1.x; cx[5]=a1.y; cx[6]=a1.z; cx[7]=a1.w;

#pragma unroll
        for (int u = 0; u < 8; ++u) {
            const int slot = (u - 1) & 7;

            // pre_d[t-1] = h_{t-1}.w_out: pk products + horiz + quad reduce
            float s = fmaf(h.y, wov.y, h.x * wov.x);
            s += dpp_<QX1>(s);
            s += dpp_<QX2>(s);                  // full 8-dot, quad-replicated
            if (slot < 4) vst.x = (p == slot)     ? s : vst.x;
            else          vst.y = (p == slot - 4) ? s : vst.y;

            GRU_STEP_CORE(cx[u])

            // after u==0's select, chunk c-1 fully staged: store 8/quad
            if (u == 0 && c > wchunks) {
                pd[(c - 1) * 8 + p]     = vst.x;
                pd[(c - 1) * 8 + 4 + p] = vst.y;
            }
        }
        a0 = n0; a1 = n1;
    }

    // tail: slot 7 = sd(last step); store final chunk
    {
        float s = fmaf(h.y, wov.y, h.x * wov.x);
        s += dpp_<QX1>(s);
        s += dpp_<QX2>(s);
        vst.y = (p == 3) ? s : vst.y;
        pd[(nch - 1) * 8 + p]     = vst.x;
        pd[(nch - 1) * 8 + 4 + p] = vst.y;
    }
#undef GRU_STEP_CORE
}

// ---------------------------------------------------------------------------
// Kernel 2 (R18, proven): fractional delay with LDS-staged tap window.
// ---------------------------------------------------------------------------
#define TBLK 4096
#define WIN  (TBLK + MAXD)   // 14096 floats, 56384 B

__global__ __launch_bounds__(1024, 1) void delay_kernel(
    const float* __restrict__ pre_d,  // (NSEQ, TLEN)
    const float* __restrict__ dt,     // (NSEQ, TLEN)
    float* __restrict__ y)            // (NSEQ, TLEN)
{
    __shared__ float w[WIN];
    const int tid = threadIdx.x;
    const int n   = blockIdx.y;
    const int t0  = blockIdx.x * TBLK;

    const float* pdn = pre_d + (size_t)n * TLEN;
    const int wbase  = t0 - MAXD;            // global t of w[0]; mult of 4

    for (int i = tid; i < WIN / 4; i += 1024) {
        const int gt = wbase + i * 4;        // whole quad same sign
        float4 v = make_float4(0.f, 0.f, 0.f, 0.f);
        if (gt >= 0) v = *(const float4*)(pdn + gt);
        *(float4*)(&w[i * 4]) = v;
    }
    __syncthreads();

    const int t = t0 + tid * 4;
    const float4 d4 = *(const float4*)(dt + (size_t)n * TLEN + t);
    float dv[4] = {d4.x, d4.y, d4.z, d4.w};
    float out[4];
#pragma unroll
    for (int e = 0; e < 4; ++e) {
        const float pq  = (float)MAXD - dv[e];
        const float k0 = floorf(pq);
        const float fr = pq - k0;
        const int k0i  = (int)k0;
        const int k1i  = min(k0i + 1, MAXD);
        const int li0  = tid * 4 + e + k0i;
        const int li1  = tid * 4 + e + k1i;
        out[e] = fmaf(1.0f - fr, w[li0], fr * w[li1]);
    }
    float4 o = make_float4(out[0], out[1], out[2], out[3]);
    *(float4*)(y + (size_t)n * TLEN + t) = o;
}

extern "C" void kernel_launch(void* const* d_in, const int* in_sizes, int n_in,
                              void* d_out, int out_size, void* d_ws, size_t ws_size,
                              hipStream_t stream) {
    const float* x      = (const float*)d_in[0];
    const float* dtraj  = (const float*)d_in[1];
    const float* w_ih   = (const float*)d_in[3];
    const float* w_hh   = (const float*)d_in[4];
    const float* b_ih   = (const float*)d_in[5];
    const float* b_hh   = (const float*)d_in[6];
    const float* w_out  = (const float*)d_in[7];

    float* y     = (float*)d_out;                       // output 0: (32,1,65536)
    float* pre_d = (float*)d_out + (size_t)NSEQ * TLEN; // output 1

    // GRU: 16 chains/wave; 1 wave/block; 512x2 = 1024 blocks -> 1 wave/SIMD
    gru_kernel<<<dim3(SEGS, NSEQ / 16), dim3(64), 0, stream>>>(
        x, w_ih, w_hh, b_ih, b_hh, w_out, pre_d);

    // Delay: LDS-staged window, 512 blocks x 1024 threads
    delay_kernel<<<dim3(TLEN / TBLK, NSEQ), dim3(1024), 0, stream>>>(
        pre_d, dtraj, y);
}